// Round 2
// baseline (1154.653 us; speedup 1.0000x reference)
//
#include <hip/hip_runtime.h>

#define SCALE 0.1f
#define LN_EPS 1e-5f
#define TPB 512                 // 8 waves
#define NBLOCKS 512             // 32768 rows / 64 rows per block
#define ROWS_PER_BLOCK 64       // 8 waves * 4 iters * 2 rows

// bf16 helpers: value stored as bf16; f32 = bits<<16 (lo) or bits&0xffff0000 (hi)
#define BF_LO(u) __uint_as_float((u) << 16)
#define BF_HI(u) __uint_as_float((u) & 0xffff0000u)

__device__ inline unsigned bfpack(float lo, float hi) {
    unsigned ul = __float_as_uint(lo);
    unsigned uh = __float_as_uint(hi);
    ul = (ul + 0x7fffu + ((ul >> 16) & 1u)) >> 16;
    uh = (uh + 0x7fffu + ((uh >> 16) & 1u)) >> 16;
    return ul | (uh << 16);
}

// Down-phase: k pairs into accumulators (2 rows share the unpack)
#define DUO(u, k0)                                                    \
    { float wl = BF_LO(u), wh = BF_HI(u);                             \
      aA[k0] = fmaf(wl, va, aA[k0]); aB[k0] = fmaf(wl, vb, aB[k0]);   \
      aA[(k0)+1] = fmaf(wh, va, aA[(k0)+1]);                          \
      aB[(k0)+1] = fmaf(wh, vb, aB[(k0)+1]); }

// Up-phase: dot with broadcast dn vectors
#define UPD(u, k0)                                                    \
    { float wl = BF_LO(u), wh = BF_HI(u);                             \
      uA = fmaf(wl, dnA[k0], uA); uB = fmaf(wl, dnB[k0], uB);         \
      uA = fmaf(wh, dnA[(k0)+1], uA); uB = fmaf(wh, dnB[(k0)+1], uB); }

// LDS granule layout (both matrices): granule idx = (e*2 + h)*64 + lane,
// where e = j*4 + i indexes the lane's 12 d's: D = 256*j + 4*lane + i,
// h selects k-half (k = 8h..8h+7). Each uint4 = 8 bf16 (k ascending, pairs).
__global__ __launch_bounds__(TPB, 4)
void adapter_fused(const float* __restrict__ x,
                   const float* __restrict__ gamma,
                   const float* __restrict__ beta,
                   const float* __restrict__ w_down,
                   const float* __restrict__ b_down,
                   const float* __restrict__ w_up,
                   const float* __restrict__ b_up,
                   float* __restrict__ out)
{
    __shared__ uint4 s_wd[1536];   // gamma ⊙ w_down, bf16 packed: 24 KB
    __shared__ uint4 s_wu[1536];   // w_up transposed,  bf16 packed: 24 KB
    __shared__ float s_pB[32][16];
    __shared__ float s_pC[32][16];
    __shared__ float s_B[16];
    __shared__ float s_C[16];

    const int t    = threadIdx.x;
    const int lane = t & 63;
    const int wave = t >> 6;

    // ---- stage weights (once per block) ----
    #pragma unroll
    for (int s = 0; s < 3; ++s) {
        const int gid = t + TPB * s;        // [0, 1536)
        const int l   = gid & 63;
        const int top = gid >> 6;           // e*2 + h, [0, 24)
        const int h   = top & 1;
        const int e   = top >> 1;           // [0, 12)
        const int D   = 256 * (e >> 2) + 4 * l + (e & 3);
        const float gm = gamma[D];
        const float4 w0 = *(const float4*)(w_down + D * 16 + 8 * h);
        const float4 w1 = *(const float4*)(w_down + D * 16 + 8 * h + 4);
        uint4 pd;
        pd.x = bfpack(w0.x * gm, w0.y * gm);
        pd.y = bfpack(w0.z * gm, w0.w * gm);
        pd.z = bfpack(w1.x * gm, w1.y * gm);
        pd.w = bfpack(w1.z * gm, w1.w * gm);
        s_wd[gid] = pd;
        const int kb = 8 * h;
        uint4 pu;
        pu.x = bfpack(w_up[(kb+0)*768 + D], w_up[(kb+1)*768 + D]);
        pu.y = bfpack(w_up[(kb+2)*768 + D], w_up[(kb+3)*768 + D]);
        pu.z = bfpack(w_up[(kb+4)*768 + D], w_up[(kb+5)*768 + D]);
        pu.w = bfpack(w_up[(kb+6)*768 + D], w_up[(kb+7)*768 + D]);
        s_wu[gid] = pu;
    }
    __syncthreads();

    // ---- per-block constants: B_k = sum_D (g*wd)[D][k] (bf16-consistent),
    //      C_k = sum_D beta[D]*wd[D][k] + b_down[k] ----
    {
        const int k = t & 15, c = t >> 4;   // c in [0, 32): 24 D's each
        const unsigned* swd32 = (const unsigned*)s_wd;
        float pb = 0.f, pc = 0.f;
        for (int m = 0; m < 24; ++m) {
            const int D  = 24 * c + m;
            const int l  = (D >> 2) & 63;
            const int e  = (D >> 8) * 4 + (D & 3);
            const int gi = (e * 2 + (k >> 3)) * 64 + l;
            const unsigned dw = swd32[gi * 4 + ((k >> 1) & 3)];
            pb += (k & 1) ? BF_HI(dw) : BF_LO(dw);
            pc += beta[D] * w_down[D * 16 + k];
        }
        s_pB[c][k] = pb; s_pC[c][k] = pc;
    }
    __syncthreads();
    if (t < 16) {
        float sb = 0.f, sc = 0.f;
        for (int c = 0; c < 32; ++c) { sb += s_pB[c][t]; sc += s_pC[c][t]; }
        s_B[t] = sb;
        s_C[t] = sc + b_down[t];
    }
    __syncthreads();

    const float Bk = s_B[lane & 15];
    const float Ck = s_C[lane & 15];

    float bu[12];
    #pragma unroll
    for (int j = 0; j < 3; ++j)
        *(float4*)&bu[4*j] = *(const float4*)(b_up + 256*j + 4*lane);

    const float inv_d = 1.0f / 768.0f;

    #pragma unroll 1
    for (int it = 0; it < 4; ++it) {
        const int row0 = blockIdx.x * ROWS_PER_BLOCK + wave * 8 + it * 2;
        const float* xr0 = x + (size_t)row0 * 768;
        const float* xr1 = xr0 + 768;

        float xa[12], xb[12];
        #pragma unroll
        for (int j = 0; j < 3; ++j) {
            *(float4*)&xa[4*j] = *(const float4*)(xr0 + 256*j + 4*lane);
            *(float4*)&xb[4*j] = *(const float4*)(xr1 + 256*j + 4*lane);
        }

        float s1a = 0.f, s2a = 0.f, s1b = 0.f, s2b = 0.f;
        float aA[16], aB[16];
        #pragma unroll
        for (int k = 0; k < 16; ++k) { aA[k] = 0.f; aB[k] = 0.f; }

        // ---- down-proj partials + LN stats ----
        #pragma unroll
        for (int e = 0; e < 12; ++e) {
            const float va = xa[e], vb = xb[e];
            s1a += va; s2a = fmaf(va, va, s2a);
            s1b += vb; s2b = fmaf(vb, vb, s2b);
            const int gb = e * 128 + lane;
            const uint4 W0 = s_wd[gb];
            const uint4 W1 = s_wd[gb + 64];
            DUO(W0.x, 0)  DUO(W0.y, 2)  DUO(W0.z, 4)  DUO(W0.w, 6)
            DUO(W1.x, 8)  DUO(W1.y, 10) DUO(W1.z, 12) DUO(W1.w, 14)
        }

        // ---- intra-wave reductions ----
        #pragma unroll
        for (int m = 8; m >= 1; m >>= 1) {
            const bool up = (lane & m) != 0;
            #pragma unroll
            for (int i = 0; i < m; ++i) {
                float sa = up ? aA[i] : aA[i+m];
                float ra = __shfl_xor(sa, m, 64);
                aA[i] = (up ? aA[i+m] : aA[i]) + ra;
                float sb = up ? aB[i] : aB[i+m];
                float rb = __shfl_xor(sb, m, 64);
                aB[i] = (up ? aB[i+m] : aB[i]) + rb;
            }
        }
        float vA = aA[0]; vA += __shfl_xor(vA, 16, 64); vA += __shfl_xor(vA, 32, 64);
        float vB = aB[0]; vB += __shfl_xor(vB, 16, 64); vB += __shfl_xor(vB, 32, 64);
        #pragma unroll
        for (int m = 32; m >= 1; m >>= 1) {
            s1a += __shfl_xor(s1a, m, 64); s2a += __shfl_xor(s2a, m, 64);
            s1b += __shfl_xor(s1b, m, 64); s2b += __shfl_xor(s2b, m, 64);
        }

        const float meanA = s1a * inv_d;
        const float rsA   = rsqrtf(fmaf(s2a, inv_d, -(meanA*meanA)) + LN_EPS);
        const float meanB = s1b * inv_d;
        const float rsB   = rsqrtf(fmaf(s2b, inv_d, -(meanB*meanB)) + LN_EPS);
        const float dva = fmaxf(fmaf(rsA, fmaf(-meanA, Bk, vA), Ck), 0.f);
        const float dvb = fmaxf(fmaf(rsB, fmaf(-meanB, Bk, vB), Ck), 0.f);

        // broadcast the 16 down values to all lanes
        float dnA[16], dnB[16];
        #pragma unroll
        for (int k = 0; k < 16; ++k) {
            dnA[k] = __shfl(dva, k, 64);
            dnB[k] = __shfl(dvb, k, 64);
        }

        // ---- up-proj + scale + residual ----
        float ua[12], ub[12];
        #pragma unroll
        for (int e = 0; e < 12; ++e) {
            const int gb = e * 128 + lane;
            const uint4 U0 = s_wu[gb];
            const uint4 U1 = s_wu[gb + 64];
            float uA = 0.f, uB = 0.f;
            UPD(U0.x, 0)  UPD(U0.y, 2)  UPD(U0.z, 4)  UPD(U0.w, 6)
            UPD(U1.x, 8)  UPD(U1.y, 10) UPD(U1.z, 12) UPD(U1.w, 14)
            ua[e] = fmaf(SCALE, uA + bu[e], xa[e]);
            ub[e] = fmaf(SCALE, uB + bu[e], xb[e]);
        }

        float* or0 = out + (size_t)row0 * 768;
        float* or1 = or0 + 768;
        #pragma unroll
        for (int j = 0; j < 3; ++j) {
            *(float4*)(or0 + 256*j + 4*lane) = *(const float4*)&ua[4*j];
            *(float4*)(or1 + 256*j + 4*lane) = *(const float4*)&ub[4*j];
        }
    }
}

extern "C" void kernel_launch(void* const* d_in, const int* in_sizes, int n_in,
                              void* d_out, int out_size, void* d_ws, size_t ws_size,
                              hipStream_t stream) {
    const float* x      = (const float*)d_in[0];
    const float* gamma  = (const float*)d_in[1];
    const float* beta   = (const float*)d_in[2];
    const float* w_down = (const float*)d_in[3];
    const float* b_down = (const float*)d_in[4];
    const float* w_up   = (const float*)d_in[5];
    const float* b_up   = (const float*)d_in[6];
    float* out = (float*)d_out;

    adapter_fused<<<NBLOCKS, TPB, 0, stream>>>(x, gamma, beta, w_down, b_down,
                                               w_up, b_up, out);
}